// Round 12
// baseline (80.843 us; speedup 1.0000x reference)
//
#include <hip/hip_runtime.h>
#include <hip/hip_bf16.h>

typedef __attribute__((ext_vector_type(8))) short bf16x8;
typedef __attribute__((ext_vector_type(4))) float f32x4;

#define B_ 2048
#define S_ 200
#define D_ 128
#define H_ 64
#define NT 13
#define LOG2E 1.44269504f

// ws layout
#define WS_TA 0u                        // f32 tA[2048][64]          = 512 KB
#define WS_AC (512u*1024u)              // f32 acT[64][128] (W1a+W1c)=  32 KB
#define WS_BC (512u*1024u + 32768u)     // f32 bcT[64][128] (W1b-W1c)=  32 KB
#define WS_DT (512u*1024u + 65536u)     // f32 dT [64][128] (W1d)    =  32 KB

static __device__ __forceinline__ short f2bf_hw(float f) {
    return (short)__builtin_bit_cast(unsigned short, __float2bfloat16(f));  // RNE
}

static __device__ __forceinline__ void gload16(const void* g, void* l) {
    // LDS dest = wave-uniform base + lane*16 ; global addr is per-lane
    __builtin_amdgcn_global_load_lds(
        (const __attribute__((address_space(1))) unsigned int*)g,
        (__attribute__((address_space(3))) unsigned int*)l, 16, 0, 0);
}

// ---- prep A: fold + transpose W1 into acT/bcT/dT (k-contiguous) ----
__global__ __launch_bounds__(128)
void prep_fold(const float* __restrict__ W1, char* __restrict__ ws)
{
    const int n = blockIdx.x;       // 64 blocks
    const int k = threadIdx.x;      // 128 threads
    float a = W1[k * H_ + n];
    float b = W1[(128 + k) * H_ + n];
    float c = W1[(256 + k) * H_ + n];
    float d = W1[(384 + k) * H_ + n];
    ((float*)(ws + WS_AC))[n * 128 + k] = a + c;
    ((float*)(ws + WS_BC))[n * 128 + k] = b - c;
    ((float*)(ws + WS_DT))[n * 128 + k] = d;
}

// ---- prep B: exact fp32 tA[b][n] = t.(W1a+W1c) + b1 ; 4 batches per block ----
__global__ __launch_bounds__(256)
void prep_ta(const float* __restrict__ tgt, const float* __restrict__ b1,
             char* __restrict__ ws)
{
    __shared__ float tl[4][128];
    const int tid = threadIdx.x;
    const int b0 = blockIdx.x * 4;
    if (tid < 128) {
        int bb = tid >> 5, q = tid & 31;
        *(float4*)&tl[bb][q * 4] = ((const float4*)(tgt + (size_t)(b0 + bb) * D_))[q];
    }
    __syncthreads();
    const int n = tid & 63, bb = tid >> 6;
    const float* ac = (const float*)(ws + WS_AC) + n * 128;
    float s = 0.f;
    #pragma unroll 8
    for (int d = 0; d < 128; ++d) s = fmaf(tl[bb][d], ac[d], s);
    ((float*)(ws + WS_TA))[(size_t)(b0 + bb) * H_ + n] = s + b1[n];
}

// ---- fused: block = batch; 4 waves SHARE the tile stream (coop staging,
// counted vmcnt + raw s_barrier). QK redundant per wave (identical softmax,
// zero cross-wave traffic); PV split by d-quarter. LDS 40 KB -> 4 blocks/CU
// = 16 waves/CU = 4 waves/SIMD (2x R11's TLP). ----
__global__ __launch_bounds__(256, 4)
void din_fused(const float* __restrict__ tgt, const float* __restrict__ hist,
               const int* __restrict__ mask, const float* __restrict__ W2,
               const char* __restrict__ ws, float* __restrict__ out)
{
    __shared__ __align__(16) char L[40960];   // [0,16K) W'' ; bufs @16K,24K,32K
    const int tid  = threadIdx.x;
    const int lane = tid & 63;
    const int wv   = tid >> 6;
    const int b    = blockIdx.x;
    const int lo   = lane & 15;
    const int hi   = lane >> 4;

    // --- prologue loads (drained by the one __syncthreads below) ---
    int mbits = 0;
    {
        const int* mp = mask + (size_t)b * S_;
        #pragma unroll
        for (int t = 0; t < NT; ++t) {
            int s = (t << 4) + lo;
            int m = (s < S_) ? mp[s] : 0;
            mbits |= (m != 0) << t;
        }
    }
    f32x4 tav[4], w2v[4];
    #pragma unroll
    for (int ng = 0; ng < 4; ++ng) {
        tav[ng] = *(const f32x4*)((const float*)(ws + WS_TA) + (size_t)b * H_ + ng * 16 + hi * 4);
        f32x4 wl = *(const f32x4*)(W2 + ng * 16 + hi * 4);
        w2v[ng] = (f32x4){wl[0] * LOG2E, wl[1] * LOG2E, wl[2] * LOG2E, wl[3] * LOG2E};
    }

    // --- cooperative W'' build (1024 chunks / 256 threads) ---
    // W''[k][n] = (W1b-W1c)[k][n] + t[k]*W1d[k][n], bf16, [n][k] XOR-swizzled
    {
        const float* bcT = (const float*)(ws + WS_BC);
        const float* dT  = (const float*)(ws + WS_DT);
        const int kb = tid & 15;
        f32x4 t0 = *(const f32x4*)(tgt + (size_t)b * D_ + kb * 8);
        f32x4 t1 = *(const f32x4*)(tgt + (size_t)b * D_ + kb * 8 + 4);
        #pragma unroll
        for (int j = 0; j < 4; ++j) {
            int n = (tid >> 4) + j * 16;
            f32x4 bc0 = *(const f32x4*)(bcT + n * 128 + kb * 8);
            f32x4 bc1 = *(const f32x4*)(bcT + n * 128 + kb * 8 + 4);
            f32x4 dd0 = *(const f32x4*)(dT  + n * 128 + kb * 8);
            f32x4 dd1 = *(const f32x4*)(dT  + n * 128 + kb * 8 + 4);
            bf16x8 v;
            #pragma unroll
            for (int e = 0; e < 4; ++e) {
                v[e]     = f2bf_hw(fmaf(t0[e], dd0[e], bc0[e]));
                v[e + 4] = f2bf_hw(fmaf(t1[e], dd1[e], bc1[e]));
            }
            *(bf16x8*)(L + n * 256 + ((kb * 16) ^ ((n & 7) << 4))) = v;
        }
    }

    // --- coop stage: 8 glls/tile split 2 per wave (own-vmcnt countable) ---
    const char* hb = (const char*)hist + (size_t)b * (S_ * D_ * 4);
    const int cp = (lane & 31) * 16;
    const int h5 = lane >> 5;
    auto stage = [&](int t, char* bufp) {
        #pragma unroll
        for (int j = 0; j < 2; ++j) {
            int i = wv * 2 + j;
            int r = 2 * i + h5;
            int s = (t << 4) + r;
            s = s > S_ - 1 ? S_ - 1 : s;
            gload16(hb + s * 512 + (cp ^ ((r & 7) << 4)), bufp + i * 1024);
        }
    };
    stage(0, L + 16384);
    stage(1, L + 24576);
    stage(2, L + 32768);
    __syncthreads();   // W'' visible; prologue + tiles 0-2 fully drained

    // swizzled LDS read offsets
    int abase[4], akoff[4];
    #pragma unroll
    for (int ng = 0; ng < 4; ++ng) abase[ng] = (ng * 16 + lo) * 256;
    #pragma unroll
    for (int ks = 0; ks < 4; ++ks) akoff[ks] = (ks * 64 + hi * 16) ^ ((lo & 7) << 4);
    const int rb  = (lo * 512 + hi * 32) ^ ((lo & 7) << 4);              // QK (per ks: +ks*128)
    const int prb = (lo * 512 + wv * 128 + hi * 32) ^ ((lo & 7) << 4);   // PV d-quarter

    float o[8];
    #pragma unroll
    for (int e = 0; e < 8; ++e) o[e] = 0.f;
    float l = 0.f, mx = -1e30f;

    auto compt = [&](int t, char* buf, bool dostage) {
        // ALL reads of this buffer happen before barrier #2
        f32x4 h0[4], h1[4];
        #pragma unroll
        for (int ks = 0; ks < 4; ++ks) {
            int o4 = rb + ks * 128;
            h0[ks] = *(const f32x4*)(buf + o4);
            h1[ks] = *(const f32x4*)(buf + (o4 ^ 16));
        }
        f32x4 q0 = *(const f32x4*)(buf + prb);
        f32x4 q1 = *(const f32x4*)(buf + (prb ^ 16));
        asm volatile("s_waitcnt lgkmcnt(0)" ::: "memory");
        __builtin_amdgcn_sched_barrier(0);
        __builtin_amdgcn_s_barrier();        // barrier #2: whole block done reading buf
        if (dostage) stage(t + 3, buf);      // overwrite with tile t+3 (same slot)

        // QK (redundant across waves -> identical softmax, no merge)
        f32x4 acc[4];
        #pragma unroll
        for (int ng = 0; ng < 4; ++ng) acc[ng] = (f32x4){0.f, 0.f, 0.f, 0.f};
        #pragma unroll
        for (int ks = 0; ks < 4; ++ks) {
            bf16x8 bfr;
            #pragma unroll
            for (int e = 0; e < 4; ++e) {
                bfr[e]     = f2bf_hw(h0[ks][e]);
                bfr[e + 4] = f2bf_hw(h1[ks][e]);
            }
            #pragma unroll
            for (int ng = 0; ng < 4; ++ng) {
                bf16x8 af = *(const bf16x8*)(L + abase[ng] + akoff[ks]);
                acc[ng] = __builtin_amdgcn_mfma_f32_16x16x32_bf16(af, bfr, acc[ng], 0, 0, 0);
            }
        }
        float s0 = 0.f, s1 = 0.f, s2 = 0.f, s3 = 0.f;
        #pragma unroll
        for (int e = 0; e < 4; ++e) {
            s0 = fmaf(fmaxf(acc[0][e] + tav[0][e], 0.f), w2v[0][e], s0);
            s1 = fmaf(fmaxf(acc[1][e] + tav[1][e], 0.f), w2v[1][e], s1);
            s2 = fmaf(fmaxf(acc[2][e] + tav[2][e], 0.f), w2v[2][e], s2);
            s3 = fmaf(fmaxf(acc[3][e] + tav[3][e], 0.f), w2v[3][e], s3);
        }
        float sum = (s0 + s1) + (s2 + s3);
        sum += __shfl_xor(sum, 16);
        sum += __shfl_xor(sum, 32);
        const int mv = (mbits >> t) & 1;
        float lg = mv ? sum : -1e30f;
        float tm = lg;
        tm = fmaxf(tm, __shfl_xor(tm, 1));
        tm = fmaxf(tm, __shfl_xor(tm, 2));
        tm = fmaxf(tm, __shfl_xor(tm, 4));
        tm = fmaxf(tm, __shfl_xor(tm, 8));
        if (tm > mx + 11.5f) {               // defer-rescale (T13)
            float r = exp2f(mx - tm);
            #pragma unroll
            for (int e = 0; e < 8; ++e) o[e] *= r;
            l *= r;
            mx = tm;
        }
        float p = mv ? exp2f(lg - mx) : 0.f;
        l += p;
        // PV: this wave's d-quarter only
        o[0] = fmaf(p, q0[0], o[0]);
        o[1] = fmaf(p, q0[1], o[1]);
        o[2] = fmaf(p, q0[2], o[2]);
        o[3] = fmaf(p, q0[3], o[3]);
        o[4] = fmaf(p, q1[0], o[4]);
        o[5] = fmaf(p, q1[1], o[5]);
        o[6] = fmaf(p, q1[2], o[6]);
        o[7] = fmaf(p, q1[3], o[7]);
    };

    // --- 13 tiles: [wait own vmcnt][barrier #1][body] ; stages at t=0..9 ---
    char* bp = L + 16384;
    #pragma unroll 1
    for (int t = 0; t < 11; ++t) {
        asm volatile("s_waitcnt vmcnt(4)" ::: "memory");   // own tile-t glls landed
        __builtin_amdgcn_s_barrier();                      // => all waves' landed
        __builtin_amdgcn_sched_barrier(0);
        compt(t, bp, t < 10);
        bp += 8192; if (bp > L + 32768) bp = L + 16384;
    }
    asm volatile("s_waitcnt vmcnt(2)" ::: "memory");
    __builtin_amdgcn_s_barrier();
    __builtin_amdgcn_sched_barrier(0);
    compt(11, bp, false);
    bp += 8192; if (bp > L + 32768) bp = L + 16384;
    asm volatile("s_waitcnt vmcnt(0)" ::: "memory");
    __builtin_amdgcn_s_barrier();
    __builtin_amdgcn_sched_barrier(0);
    compt(12, bp, false);

    // --- epilogue: lo-reduce o and l; lanes lo==0 store this wave's d-quarter ---
    #pragma unroll
    for (int e = 0; e < 8; ++e) {
        float v = o[e];
        v += __shfl_xor(v, 1);
        v += __shfl_xor(v, 2);
        v += __shfl_xor(v, 4);
        v += __shfl_xor(v, 8);
        o[e] = v;
    }
    l += __shfl_xor(l, 1);
    l += __shfl_xor(l, 2);
    l += __shfl_xor(l, 4);
    l += __shfl_xor(l, 8);

    const float inv = 1.0f / l;             // mx, b2 cancel in softmax
    if (lo == 0) {
        float* op = out + (size_t)b * D_ + wv * 32 + hi * 8;
        *(f32x4*)op       = (f32x4){o[0] * inv, o[1] * inv, o[2] * inv, o[3] * inv};
        *(f32x4*)(op + 4) = (f32x4){o[4] * inv, o[5] * inv, o[6] * inv, o[7] * inv};
    }
}

extern "C" void kernel_launch(void* const* d_in, const int* in_sizes, int n_in,
                              void* d_out, int out_size, void* d_ws, size_t ws_size,
                              hipStream_t stream) {
    const float* tgt  = (const float*)d_in[0];
    const float* hist = (const float*)d_in[1];
    const int*   mask = (const int*)d_in[2];
    const float* W1   = (const float*)d_in[3];
    const float* b1   = (const float*)d_in[4];
    const float* W2   = (const float*)d_in[5];
    const float* b2   = (const float*)d_in[6];
    (void)b2;  // cancels in softmax
    float* out = (float*)d_out;
    char* ws = (char*)d_ws;

    prep_fold<<<64, 128, 0, stream>>>(W1, ws);
    prep_ta<<<B_ / 4, 256, 0, stream>>>(tgt, b1, ws);
    din_fused<<<B_, 256, 0, stream>>>(tgt, hist, mask, W2, ws, out);
}

// Round 13
// 58.776 us; speedup vs baseline: 1.3754x; 1.3754x over previous
//
#include <hip/hip_runtime.h>
#include <hip/hip_bf16.h>

typedef __attribute__((ext_vector_type(8))) short bf16x8;
typedef __attribute__((ext_vector_type(4))) float f32x4;

#define B_ 2048
#define S_ 200
#define D_ 128
#define H_ 64
#define LOG2E 1.44269504f
#define TR 14                       /* rows per tile */
#define TB (TR*512)                 /* 7168 B per buffer */

// ws layout
#define WS_TA 0u                        // f32 tA[2048][64]          = 512 KB
#define WS_AC (512u*1024u)              // f32 acT[64][128] (W1a+W1c)=  32 KB
#define WS_BC (512u*1024u + 32768u)     // f32 bcT[64][128] (W1b-W1c)=  32 KB
#define WS_DT (512u*1024u + 65536u)     // f32 dT [64][128] (W1d)    =  32 KB
#define WS_CN (512u*1024u + 98304u)     // i32 cnt|uni<<16 [2048]    =   8 KB
#define WS_LS (512u*1024u + 106496u)    // i32 list[2048][208]       = 1.7 MB

// LDS layout (din_fused): [0,16K) W'' ; [16K,16K+832) list ; bufs @17408
#define L_LIST 16384
#define L_BUF  17408

static __device__ __forceinline__ short f2bf_hw(float f) {
    return (short)__builtin_bit_cast(unsigned short, __float2bfloat16(f));  // RNE
}

static __device__ __forceinline__ void gload16(const void* g, void* l) {
    __builtin_amdgcn_global_load_lds(
        (const __attribute__((address_space(1))) unsigned int*)g,
        (__attribute__((address_space(3))) unsigned int*)l, 16, 0, 0);
}

// ---- prep A: fold + transpose W1 ----
__global__ __launch_bounds__(128)
void prep_fold(const float* __restrict__ W1, char* __restrict__ ws)
{
    const int n = blockIdx.x;
    const int k = threadIdx.x;
    float a = W1[k * H_ + n];
    float b = W1[(128 + k) * H_ + n];
    float c = W1[(256 + k) * H_ + n];
    float d = W1[(384 + k) * H_ + n];
    ((float*)(ws + WS_AC))[n * 128 + k] = a + c;
    ((float*)(ws + WS_BC))[n * 128 + k] = b - c;
    ((float*)(ws + WS_DT))[n * 128 + k] = d;
}

// ---- prep B: exact fp32 tA[b][n] ----
__global__ __launch_bounds__(256)
void prep_ta(const float* __restrict__ tgt, const float* __restrict__ b1,
             char* __restrict__ ws)
{
    __shared__ float tl[4][128];
    const int tid = threadIdx.x;
    const int b0 = blockIdx.x * 4;
    if (tid < 128) {
        int bb = tid >> 5, q = tid & 31;
        *(float4*)&tl[bb][q * 4] = ((const float4*)(tgt + (size_t)(b0 + bb) * D_))[q];
    }
    __syncthreads();
    const int n = tid & 63, bb = tid >> 6;
    const float* ac = (const float*)(ws + WS_AC) + n * 128;
    float s = 0.f;
    #pragma unroll 8
    for (int d = 0; d < 128; ++d) s = fmaf(tl[bb][d], ac[d], s);
    ((float*)(ws + WS_TA))[(size_t)(b0 + bb) * H_ + n] = s + b1[n];
}

// ---- prep C: compact active rows per batch (one wave per batch) ----
__global__ __launch_bounds__(256)
void mask_build(const int* __restrict__ mask, char* __restrict__ ws)
{
    const int lane = threadIdx.x & 63;
    const int wv   = threadIdx.x >> 6;
    const int b    = blockIdx.x * 4 + wv;
    const int* mp  = mask + (size_t)b * S_;
    int* lst = (int*)(ws + WS_LS) + (size_t)b * 208;
    int cnt = 0, last = 0;
    #pragma unroll
    for (int c = 0; c < 4; ++c) {
        int s = c * 64 + lane;
        int m = (s < S_) ? mp[s] : 0;
        unsigned long long bal = __ballot(m != 0);
        if (m) lst[cnt + __builtin_popcountll(bal & ((1ull << lane) - 1ull))] = s;
        if (bal) last = c * 64 + (63 - __builtin_clzll(bal));
        cnt += __builtin_popcountll(bal);
    }
    int uni = 0;
    if (cnt == 0) { uni = 1; cnt = S_; }
    for (int p = cnt + lane; p < 208; p += 64) lst[p] = uni ? (S_ - 1) : last;
    if (uni)
        for (int p = lane; p < S_; p += 64) lst[p] = p;
    if (lane == 0) ((int*)(ws + WS_CN))[b] = cnt | (uni << 16);
}

// ---- fused: block = batch; 4 waves, per-wave private 2-deep pipeline over
// COMPACTED active-row tiles (14 rows); counted vmcnt(7); flash merge. ----
__global__ __launch_bounds__(256) __attribute__((amdgpu_waves_per_eu(2, 2)))
void din_fused(const float* __restrict__ tgt, const float* __restrict__ hist,
               const float* __restrict__ W2, const char* __restrict__ ws,
               float* __restrict__ out)
{
    __shared__ __align__(16) char L[L_BUF + 4 * 2 * TB];   // 74752 B -> 2 blocks/CU
    const int tid  = threadIdx.x;
    const int lane = tid & 63;
    const int wv   = tid >> 6;
    const int b    = blockIdx.x;
    const int lo   = lane & 15;
    const int hi   = lane >> 4;

    // --- prologue (all VMEM here drains at the build __syncthreads) ---
    const int cw  = ((const int*)(ws + WS_CN))[b];
    const int cnt = cw & 0xffff;
    const int uni = cw >> 16;
    const int nt  = (cnt + TR - 1) / TR;

    if (tid < 52)
        ((int4*)(L + L_LIST))[tid] = ((const int4*)(ws + WS_LS + (size_t)b * 832u))[tid];

    f32x4 tav[4], w2v[4];
    #pragma unroll
    for (int ng = 0; ng < 4; ++ng) {
        tav[ng] = *(const f32x4*)((const float*)(ws + WS_TA) + (size_t)b * H_ + ng * 16 + hi * 4);
        f32x4 wl = *(const f32x4*)(W2 + ng * 16 + hi * 4);
        w2v[ng] = (f32x4){wl[0] * LOG2E, wl[1] * LOG2E, wl[2] * LOG2E, wl[3] * LOG2E};
    }

    // --- cooperative W'' build (1024 chunks / 256 threads) ---
    {
        const float* bcT = (const float*)(ws + WS_BC);
        const float* dT  = (const float*)(ws + WS_DT);
        const int kb = tid & 15;
        f32x4 t0 = *(const f32x4*)(tgt + (size_t)b * D_ + kb * 8);
        f32x4 t1 = *(const f32x4*)(tgt + (size_t)b * D_ + kb * 8 + 4);
        #pragma unroll
        for (int j = 0; j < 4; ++j) {
            int n = (tid >> 4) + j * 16;
            f32x4 bc0 = *(const f32x4*)(bcT + n * 128 + kb * 8);
            f32x4 bc1 = *(const f32x4*)(bcT + n * 128 + kb * 8 + 4);
            f32x4 dd0 = *(const f32x4*)(dT  + n * 128 + kb * 8);
            f32x4 dd1 = *(const f32x4*)(dT  + n * 128 + kb * 8 + 4);
            bf16x8 v;
            #pragma unroll
            for (int e = 0; e < 4; ++e) {
                v[e]     = f2bf_hw(fmaf(t0[e], dd0[e], bc0[e]));
                v[e + 4] = f2bf_hw(fmaf(t1[e], dd1[e], bc1[e]));
            }
            *(bf16x8*)(L + n * 256 + ((kb * 16) ^ ((n & 7) << 4))) = v;
        }
    }
    __syncthreads();   // W'' + list visible; ALL prologue VMEM drained (vmcnt=0)

    // --- addresses ---
    int abase[4], akoff[4];
    #pragma unroll
    for (int ng = 0; ng < 4; ++ng) abase[ng] = (ng * 16 + lo) * 256;
    #pragma unroll
    for (int ks = 0; ks < 4; ++ks) akoff[ks] = (ks * 64 + hi * 16) ^ ((lo & 7) << 4);
    const int loc = lo > TR - 1 ? TR - 1 : lo;           // clamp row slot (finite data)
    const int rb  = (loc * 512 + hi * 32) ^ ((loc & 7) << 4);
    const int prb = (loc * 512 + wv * 0 + hi * 32) ^ ((loc & 7) << 4);  // same row; PV uses all ks
    char* B0 = L + L_BUF + wv * (2 * TB);
    char* B1 = B0 + TB;

    const char* hb = (const char*)hist + (size_t)b * (S_ * D_ * 4);
    const int cp = (lane & 31) * 16;
    const int h5 = lane >> 5;
    const int* ll = (const int*)(L + L_LIST);

    auto stage_pos = [&](int t, char* bufp) {            // cold path (indices exposed)
        int rr[7];
        #pragma unroll
        for (int i = 0; i < 7; ++i) rr[i] = ll[t * TR + 2 * i + h5];
        #pragma unroll
        for (int i = 0; i < 7; ++i)
            gload16(hb + (size_t)rr[i] * 512 + (cp ^ (((2 * i + h5) & 7) << 4)),
                    bufp + i * 1024);
    };

    float o[4][8];
    #pragma unroll
    for (int ks = 0; ks < 4; ++ks)
        #pragma unroll
        for (int e = 0; e < 8; ++e) o[ks][e] = 0.f;
    float l = 0.f, mx = -1e30f;

    auto compt = [&](int t, char* buf, int nxt) {
        // prefetch next-tile indices (LDS, latency hidden under this tile)
        int r[7];
        if (nxt >= 0) {
            #pragma unroll
            for (int i = 0; i < 7; ++i) r[i] = ll[nxt * TR + 2 * i + h5];
        }
        // read this tile (QK + PV rows) before overwrite
        f32x4 h0[4], h1[4];
        #pragma unroll
        for (int ks = 0; ks < 4; ++ks) {
            int o4 = rb + ks * 128;
            h0[ks] = *(const f32x4*)(buf + o4);
            h1[ks] = *(const f32x4*)(buf + (o4 ^ 16));
        }
        asm volatile("s_waitcnt lgkmcnt(0)" ::: "memory");
        __builtin_amdgcn_sched_barrier(0);
        if (nxt >= 0) {
            #pragma unroll
            for (int i = 0; i < 7; ++i)
                gload16(hb + (size_t)r[i] * 512 + (cp ^ (((2 * i + h5) & 7) << 4)),
                        buf + i * 1024);
        }
        // QK: bf16 fragments + swapped MFMA (D[n,s])
        f32x4 acc[4];
        #pragma unroll
        for (int ng = 0; ng < 4; ++ng) acc[ng] = (f32x4){0.f, 0.f, 0.f, 0.f};
        #pragma unroll
        for (int ks = 0; ks < 4; ++ks) {
            bf16x8 bfr;
            #pragma unroll
            for (int e = 0; e < 4; ++e) {
                bfr[e]     = f2bf_hw(h0[ks][e]);
                bfr[e + 4] = f2bf_hw(h1[ks][e]);
            }
            #pragma unroll
            for (int ng = 0; ng < 4; ++ng) {
                bf16x8 af = *(const bf16x8*)(L + abase[ng] + akoff[ks]);
                acc[ng] = __builtin_amdgcn_mfma_f32_16x16x32_bf16(af, bfr, acc[ng], 0, 0, 0);
            }
        }
        float s0 = 0.f, s1 = 0.f, s2 = 0.f, s3 = 0.f;
        #pragma unroll
        for (int e = 0; e < 4; ++e) {
            s0 = fmaf(fmaxf(acc[0][e] + tav[0][e], 0.f), w2v[0][e], s0);
            s1 = fmaf(fmaxf(acc[1][e] + tav[1][e], 0.f), w2v[1][e], s1);
            s2 = fmaf(fmaxf(acc[2][e] + tav[2][e], 0.f), w2v[2][e], s2);
            s3 = fmaf(fmaxf(acc[3][e] + tav[3][e], 0.f), w2v[3][e], s3);
        }
        float sum = (s0 + s1) + (s2 + s3);
        sum += __shfl_xor(sum, 16);
        sum += __shfl_xor(sum, 32);
        const bool valid = (t * TR + lo < cnt) && (lo < TR);
        float lg = uni ? (valid ? 0.f : -1e30f) : (valid ? sum : -1e30f);
        float tm = lg;
        tm = fmaxf(tm, __shfl_xor(tm, 1));
        tm = fmaxf(tm, __shfl_xor(tm, 2));
        tm = fmaxf(tm, __shfl_xor(tm, 4));
        tm = fmaxf(tm, __shfl_xor(tm, 8));
        if (tm > mx + 11.5f) {               // defer-rescale (T13)
            float rsc = exp2f(mx - tm);
            #pragma unroll
            for (int ks = 0; ks < 4; ++ks)
                #pragma unroll
                for (int e = 0; e < 8; ++e) o[ks][e] *= rsc;
            l *= rsc;
            mx = tm;
        }
        float p = valid ? exp2f(lg - mx) : 0.f;
        l += p;
        #pragma unroll
        for (int ks = 0; ks < 4; ++ks) {
            o[ks][0] = fmaf(p, h0[ks][0], o[ks][0]);
            o[ks][1] = fmaf(p, h0[ks][1], o[ks][1]);
            o[ks][2] = fmaf(p, h0[ks][2], o[ks][2]);
            o[ks][3] = fmaf(p, h0[ks][3], o[ks][3]);
            o[ks][4] = fmaf(p, h1[ks][0], o[ks][4]);
            o[ks][5] = fmaf(p, h1[ks][1], o[ks][5]);
            o[ks][6] = fmaf(p, h1[ks][2], o[ks][6]);
            o[ks][7] = fmaf(p, h1[ks][3], o[ks][7]);
        }
    };

    // --- per-wave runtime pipeline over tiles wv, wv+4, ... < nt ---
    const int ntw = (nt > wv) ? ((nt - wv + 3) >> 2) : 0;
    if (ntw > 0) {
        stage_pos(wv, B0);
        if (ntw > 1) stage_pos(wv + 4, B1);
        #pragma unroll 1
        for (int j = 0; j + 2 < ntw; ++j) {
            char* bj = (j & 1) ? B1 : B0;
            asm volatile("s_waitcnt vmcnt(7)" ::: "memory");   // tile j landed
            compt(wv + 4 * j, bj, wv + 4 * j + 8);
        }
        if (ntw >= 2) {
            char* bA = ((ntw - 2) & 1) ? B1 : B0;
            char* bB = ((ntw - 1) & 1) ? B1 : B0;
            asm volatile("s_waitcnt vmcnt(7)" ::: "memory");
            compt(wv + 4 * (ntw - 2), bA, -1);
            asm volatile("s_waitcnt vmcnt(0)" ::: "memory");
            compt(wv + 4 * (ntw - 1), bB, -1);
        } else {
            asm volatile("s_waitcnt vmcnt(0)" ::: "memory");
            compt(wv, B0, -1);
        }
    }

    // --- per-wave lo-reduce, publish, 4-way flash merge ---
    #pragma unroll
    for (int ks = 0; ks < 4; ++ks)
        #pragma unroll
        for (int e = 0; e < 8; ++e) {
            float v = o[ks][e];
            v += __shfl_xor(v, 1);
            v += __shfl_xor(v, 2);
            v += __shfl_xor(v, 4);
            v += __shfl_xor(v, 8);
            o[ks][e] = v;
        }
    l += __shfl_xor(l, 1);
    l += __shfl_xor(l, 2);
    l += __shfl_xor(l, 4);
    l += __shfl_xor(l, 8);

    float* mo = (float*)B0;                 // wave-private; pipeline fully drained
    if (lo == 0) {
        #pragma unroll
        for (int ks = 0; ks < 4; ++ks) {
            *(f32x4*)(mo + ks * 32 + hi * 8)     = (f32x4){o[ks][0], o[ks][1], o[ks][2], o[ks][3]};
            *(f32x4*)(mo + ks * 32 + hi * 8 + 4) = (f32x4){o[ks][4], o[ks][5], o[ks][6], o[ks][7]};
        }
        if (hi == 0) { mo[128] = mx; mo[129] = l; }
    }
    __syncthreads();

    if (tid < 128) {
        const float* m0 = (const float*)(L + L_BUF);
        const float* m1 = (const float*)(L + L_BUF + 2 * TB);
        const float* m2 = (const float*)(L + L_BUF + 4 * TB);
        const float* m3 = (const float*)(L + L_BUF + 6 * TB);
        float mstar = fmaxf(fmaxf(m0[128], m1[128]), fmaxf(m2[128], m3[128]));
        float f0 = exp2f(m0[128] - mstar), f1 = exp2f(m1[128] - mstar);
        float f2 = exp2f(m2[128] - mstar), f3 = exp2f(m3[128] - mstar);
        float num = m0[tid] * f0 + m1[tid] * f1 + m2[tid] * f2 + m3[tid] * f3;
        float den = m0[129] * f0 + m1[129] * f1 + m2[129] * f2 + m3[129] * f3;
        out[(size_t)b * D_ + tid] = num / den;   // b2 cancels in softmax
    }
}

extern "C" void kernel_launch(void* const* d_in, const int* in_sizes, int n_in,
                              void* d_out, int out_size, void* d_ws, size_t ws_size,
                              hipStream_t stream) {
    const float* tgt  = (const float*)d_in[0];
    const float* hist = (const float*)d_in[1];
    const int*   mask = (const int*)d_in[2];
    const float* W1   = (const float*)d_in[3];
    const float* b1   = (const float*)d_in[4];
    const float* W2   = (const float*)d_in[5];
    const float* b2   = (const float*)d_in[6];
    (void)b2;  // cancels in softmax
    float* out = (float*)d_out;
    char* ws = (char*)d_ws;

    prep_fold<<<64, 128, 0, stream>>>(W1, ws);
    prep_ta<<<B_ / 4, 256, 0, stream>>>(tgt, b1, ws);
    mask_build<<<B_ / 4, 256, 0, stream>>>(mask, ws);
    din_fused<<<B_, 256, 0, stream>>>(tgt, hist, W2, ws, out);
}

// Round 14
// 57.718 us; speedup vs baseline: 1.4006x; 1.0183x over previous
//
#include <hip/hip_runtime.h>
#include <hip/hip_bf16.h>

typedef __attribute__((ext_vector_type(8))) short bf16x8;
typedef __attribute__((ext_vector_type(4))) float f32x4;

#define B_ 2048
#define S_ 200
#define D_ 128
#define H_ 64
#define LOG2E 1.44269504f
#define TR 8                      /* rows per tile */
#define TB 4096                   /* bytes per hist buffer (8 rows x 512B) */

// ws layout
#define WS_AC 0u                  // f32 acT[64][128] (W1a+W1c)      = 32 KB
#define WS_WB 32768u              // bf16 W' [n=64][k=256] swizzled  = 32 KB
#define WS_MT 65536u              // meta[2048][2048 B]              =  4 MB
// meta block: [0,512) t fp32 | [512,768) tA fp32 | [768] cnt|uni<<16 | [1024,1856) list i32[208]

static __device__ __forceinline__ short f2bf_hw(float f) {
    return (short)__builtin_bit_cast(unsigned short, __float2bfloat16(f));  // RNE
}

static __device__ __forceinline__ void gload16(const void* g, void* l) {
    // LDS dest = wave-uniform base + lane*16 ; global src addr is per-lane
    __builtin_amdgcn_global_load_lds(
        (const __attribute__((address_space(1))) unsigned int*)g,
        (__attribute__((address_space(3))) unsigned int*)l, 16, 0, 0);
}

// ---- prep A: acT fp32 + bf16 W' image in the exact swizzled LDS layout ----
// W'[k][n] = k<128 ? (W1b-W1c)[k][n] : W1d[k-128][n]; image row n stride 512B,
// chunk (n, k-octet kk) at n*512 + ((kk*16) ^ ((n&7)<<4)).
__global__ __launch_bounds__(128)
void prep_fold(const float* __restrict__ W1, char* __restrict__ ws)
{
    const int n = blockIdx.x;       // 64
    const int k = threadIdx.x;      // 128
    float a = W1[k * H_ + n];
    float b = W1[(128 + k) * H_ + n];
    float c = W1[(256 + k) * H_ + n];
    float d = W1[(384 + k) * H_ + n];
    ((float*)(ws + WS_AC))[n * 128 + k] = a + c;
    char* img = ws + WS_WB;
    const int sw = (n & 7) << 4;
    const int kk = k >> 3, e2 = (k & 7) * 2;
    *(short*)(img + n * 512 + ((kk * 16) ^ sw) + e2)          = f2bf_hw(b - c);
    *(short*)(img + n * 512 + (((16 + kk) * 16) ^ sw) + e2)   = f2bf_hw(d);
}

// ---- prep B: exact fp32 tA[b][n] -> meta+512 ----
__global__ __launch_bounds__(256)
void prep_ta(const float* __restrict__ tgt, const float* __restrict__ b1,
             char* __restrict__ ws)
{
    __shared__ float tl[4][128];
    const int tid = threadIdx.x;
    const int b0 = blockIdx.x * 4;
    if (tid < 128) {
        int bb = tid >> 5, q = tid & 31;
        *(float4*)&tl[bb][q * 4] = ((const float4*)(tgt + (size_t)(b0 + bb) * D_))[q];
    }
    __syncthreads();
    const int n = tid & 63, bb = tid >> 6;
    const float* ac = (const float*)(ws + WS_AC) + n * 128;
    float s = 0.f;
    #pragma unroll 8
    for (int d = 0; d < 128; ++d) s = fmaf(tl[bb][d], ac[d], s);
    ((float*)(ws + WS_MT + (size_t)(b0 + bb) * 2048u + 512u))[n] = s + b1[n];
}

// ---- prep C: compact active rows + copy t ; one wave per batch ----
__global__ __launch_bounds__(256)
void mask_build(const int* __restrict__ mask, const float* __restrict__ tgt,
                char* __restrict__ ws)
{
    const int lane = threadIdx.x & 63;
    const int wv   = threadIdx.x >> 6;
    const int b    = blockIdx.x * 4 + wv;
    const int* mp  = mask + (size_t)b * S_;
    char* mt = ws + WS_MT + (size_t)b * 2048u;
    int* lst = (int*)(mt + 1024);
    int cnt = 0, last = 0;
    #pragma unroll
    for (int c = 0; c < 4; ++c) {
        int s = c * 64 + lane;
        int m = (s < S_) ? mp[s] : 0;
        unsigned long long bal = __ballot(m != 0);
        if (m) lst[cnt + __builtin_popcountll(bal & ((1ull << lane) - 1ull))] = s;
        if (bal) last = c * 64 + (63 - __builtin_clzll(bal));
        cnt += __builtin_popcountll(bal);
    }
    int uni = 0;
    if (cnt == 0) { uni = 1; cnt = S_; }
    for (int p = cnt + lane; p < 208; p += 64) lst[p] = uni ? (S_ - 1) : last;
    if (uni)
        for (int p = lane; p < S_; p += 64) lst[p] = p;
    if (lane == 0) *(int*)(mt + 768) = cnt | (uni << 16);
    if (lane < 32) ((float4*)mt)[lane] = ((const float4*)(tgt + (size_t)b * D_))[lane];
}

// ---- fused: block = 4 batches, WAVE = 1 batch. Shared W' (32 KB) staged once;
// per-wave meta (2 KB) + 2x4 KB hist dbuf. LDS 72 KB -> 2 blocks/CU -> ALL 512
// blocks resident: ONE round, ~13-tile pipeline per wave, no flash merge. ----
__global__ __launch_bounds__(256) __attribute__((amdgpu_waves_per_eu(2, 2)))
void din_fused(const float* __restrict__ hist, const float* __restrict__ W2,
               const char* __restrict__ ws, float* __restrict__ out)
{
    __shared__ __align__(16) char L[73728];  // [0,32K) W' ; +wv*10240: meta|B0|B1
    const int tid  = threadIdx.x;
    const int lane = tid & 63;
    const int wv   = tid >> 6;
    const int b    = blockIdx.x * 4 + wv;
    const int lo   = lane & 15;
    const int hi   = lane >> 4;
    char* Lm = L + 32768 + wv * 10240;       // meta 2 KB
    char* B0 = Lm + 2048;
    char* B1 = Lm + 6144;

    // w2 (global reg loads; drained by the prologue barrier)
    f32x4 w2v[4];
    #pragma unroll
    for (int ng = 0; ng < 4; ++ng) {
        f32x4 wl = *(const f32x4*)(W2 + ng * 16 + hi * 4);
        w2v[ng] = (f32x4){wl[0] * LOG2E, wl[1] * LOG2E, wl[2] * LOG2E, wl[3] * LOG2E};
    }

    // prologue glls: W' quarter (8 KB/wave) + meta (2 KB/wave)
    {
        const char* wsrc = ws + WS_WB + wv * 8192 + (size_t)lane * 16u;
        #pragma unroll
        for (int i = 0; i < 8; ++i)
            gload16(wsrc + i * 1024, L + wv * 8192 + i * 1024);
        const char* msrc = ws + WS_MT + (size_t)b * 2048u + (size_t)lane * 16u;
        gload16(msrc,        Lm);
        gload16(msrc + 1024, Lm + 1024);
    }
    asm volatile("s_waitcnt vmcnt(0)" ::: "memory");
    __syncthreads();                          // W' (all waves) + meta visible

    const int cw  = *(const int*)(Lm + 768);
    const int cnt = cw & 0xffff;
    const int uni = cw >> 16;
    int nt = (cnt + TR - 1) / TR; if (nt < 2) nt = 2;   // padded tiles are benign (p=0)
    const int* ll = (const int*)(Lm + 1024);

    f32x4 tav[4];
    #pragma unroll
    for (int ng = 0; ng < 4; ++ng)
        tav[ng] = *(const f32x4*)(Lm + 512 + (ng * 16 + hi * 4) * 4);

    // swizzled read offsets: A = W' (row n stride 512), hist rows (stride 512)
    int abase[4], akoff[8];
    #pragma unroll
    for (int ng = 0; ng < 4; ++ng) abase[ng] = (ng * 16 + lo) * 512;
    #pragma unroll
    for (int ks = 0; ks < 8; ++ks) akoff[ks] = (ks * 64 + hi * 16) ^ ((lo & 7) << 4);
    const int rb   = ((lo & 7) * 512 + hi * 32) ^ ((lo & 7) << 4);
    const int toff = hi * 32;

    const char* hb = (const char*)hist + (size_t)b * (S_ * D_ * 4);
    const int cp = (lane & 31) * 16;
    const int h5 = lane >> 5;

    // initial stages (list is in LDS now)
    {
        #pragma unroll
        for (int i = 0; i < 4; ++i) {
            int r = 2 * i + h5;
            gload16(hb + (size_t)ll[r] * 512 + (cp ^ ((r & 7) << 4)), B0 + i * 1024);
        }
        #pragma unroll
        for (int i = 0; i < 4; ++i) {
            int r = 2 * i + h5;
            gload16(hb + (size_t)ll[8 + r] * 512 + (cp ^ ((r & 7) << 4)), B1 + i * 1024);
        }
    }

    float o[4][8];
    #pragma unroll
    for (int ks = 0; ks < 4; ++ks)
        #pragma unroll
        for (int e = 0; e < 8; ++e) o[ks][e] = 0.f;
    float l = 0.f, mx = -1e30f;

    auto compt = [&](int t, char* buf, int nxt) {
        // next-tile indices (LDS, hidden)
        int r[4];
        if (nxt >= 0) {
            #pragma unroll
            for (int i = 0; i < 4; ++i) r[i] = ll[nxt * TR + 2 * i + h5];
        }
        // QK: K=256 = [h | t*h], per-ks transient reads
        f32x4 acc[4];
        #pragma unroll
        for (int ng = 0; ng < 4; ++ng) acc[ng] = (f32x4){0.f, 0.f, 0.f, 0.f};
        #pragma unroll
        for (int ks = 0; ks < 4; ++ks) {
            int o4 = rb + ks * 128;
            f32x4 h0  = *(const f32x4*)(buf + o4);
            f32x4 h1  = *(const f32x4*)(buf + (o4 ^ 16));
            f32x4 tp0 = *(const f32x4*)(Lm + ks * 128 + toff);
            f32x4 tp1 = *(const f32x4*)(Lm + ks * 128 + toff + 16);
            bf16x8 bh, bt;
            #pragma unroll
            for (int e = 0; e < 4; ++e) {
                bh[e]     = f2bf_hw(h0[e]);
                bh[e + 4] = f2bf_hw(h1[e]);
                bt[e]     = f2bf_hw(tp0[e] * h0[e]);   // fp32 product, then RNE
                bt[e + 4] = f2bf_hw(tp1[e] * h1[e]);
            }
            #pragma unroll
            for (int ng = 0; ng < 4; ++ng) {
                bf16x8 af = *(const bf16x8*)(L + abase[ng] + akoff[ks]);
                acc[ng] = __builtin_amdgcn_mfma_f32_16x16x32_bf16(af, bh, acc[ng], 0, 0, 0);
            }
            #pragma unroll
            for (int ng = 0; ng < 4; ++ng) {
                bf16x8 af = *(const bf16x8*)(L + abase[ng] + akoff[ks + 4]);
                acc[ng] = __builtin_amdgcn_mfma_f32_16x16x32_bf16(af, bt, acc[ng], 0, 0, 0);
            }
        }
        // lane-local relu-dot over this lane's 16 n-values; s-row = lo
        float s0 = 0.f, s1 = 0.f, s2 = 0.f, s3 = 0.f;
        #pragma unroll
        for (int e = 0; e < 4; ++e) {
            s0 = fmaf(fmaxf(acc[0][e] + tav[0][e], 0.f), w2v[0][e], s0);
            s1 = fmaf(fmaxf(acc[1][e] + tav[1][e], 0.f), w2v[1][e], s1);
            s2 = fmaf(fmaxf(acc[2][e] + tav[2][e], 0.f), w2v[2][e], s2);
            s3 = fmaf(fmaxf(acc[3][e] + tav[3][e], 0.f), w2v[3][e], s3);
        }
        float sum = (s0 + s1) + (s2 + s3);
        sum += __shfl_xor(sum, 16);
        sum += __shfl_xor(sum, 32);
        const bool valid = (t * TR + lo < cnt) && (lo < TR);
        float lg = uni ? (valid ? 0.f : -1e30f) : (valid ? sum : -1e30f);
        float tm = lg;
        tm = fmaxf(tm, __shfl_xor(tm, 1));
        tm = fmaxf(tm, __shfl_xor(tm, 2));
        tm = fmaxf(tm, __shfl_xor(tm, 4));
        tm = fmaxf(tm, __shfl_xor(tm, 8));
        if (tm > mx + 11.5f) {               // defer-rescale (T13)
            float rsc = exp2f(mx - tm);
            #pragma unroll
            for (int ks = 0; ks < 4; ++ks)
                #pragma unroll
                for (int e = 0; e < 8; ++e) o[ks][e] *= rsc;
            l *= rsc;
            mx = tm;
        }
        float p = valid ? exp2f(lg - mx) : 0.f;
        l += p;
        // PV: re-read h fp32 from LDS (keeps VGPR low), then release buf
        #pragma unroll
        for (int ks = 0; ks < 4; ++ks) {
            int o4 = rb + ks * 128;
            f32x4 h0 = *(const f32x4*)(buf + o4);
            f32x4 h1 = *(const f32x4*)(buf + (o4 ^ 16));
            o[ks][0] = fmaf(p, h0[0], o[ks][0]);
            o[ks][1] = fmaf(p, h0[1], o[ks][1]);
            o[ks][2] = fmaf(p, h0[2], o[ks][2]);
            o[ks][3] = fmaf(p, h0[3], o[ks][3]);
            o[ks][4] = fmaf(p, h1[0], o[ks][4]);
            o[ks][5] = fmaf(p, h1[1], o[ks][5]);
            o[ks][6] = fmaf(p, h1[2], o[ks][6]);
            o[ks][7] = fmaf(p, h1[3], o[ks][7]);
        }
        asm volatile("s_waitcnt lgkmcnt(0)" ::: "memory");
        __builtin_amdgcn_sched_barrier(0);
        if (nxt >= 0) {
            #pragma unroll
            for (int i = 0; i < 4; ++i)
                gload16(hb + (size_t)r[i] * 512 + (cp ^ (((2 * i + h5) & 7) << 4)),
                        buf + i * 1024);
        }
    };

    // ---- per-wave pipeline: vmcnt(4) per tile, vmcnt(0) only at the tail ----
    #pragma unroll 1
    for (int t = 0; t < nt; ++t) {
        char* buf = (t & 1) ? B1 : B0;
        if (t + 1 < nt) { asm volatile("s_waitcnt vmcnt(4)" ::: "memory"); }
        else            { asm volatile("s_waitcnt vmcnt(0)" ::: "memory"); }
        __builtin_amdgcn_sched_barrier(0);
        compt(t, buf, (t + 2 < nt) ? t + 2 : -1);
    }

    // ---- epilogue: lo-reduce, direct stores (no merge) ----
    #pragma unroll
    for (int ks = 0; ks < 4; ++ks)
        #pragma unroll
        for (int e = 0; e < 8; ++e) {
            float v = o[ks][e];
            v += __shfl_xor(v, 1);
            v += __shfl_xor(v, 2);
            v += __shfl_xor(v, 4);
            v += __shfl_xor(v, 8);
            o[ks][e] = v;
        }
    l += __shfl_xor(l, 1);
    l += __shfl_xor(l, 2);
    l += __shfl_xor(l, 4);
    l += __shfl_xor(l, 8);

    const float inv = 1.0f / l;              // mx, b2 cancel in softmax
    if (lo == 0) {
        float* op = out + (size_t)b * D_ + hi * 8;
        #pragma unroll
        for (int ks = 0; ks < 4; ++ks) {
            *(f32x4*)(op + ks * 32)     = (f32x4){o[ks][0] * inv, o[ks][1] * inv,
                                                  o[ks][2] * inv, o[ks][3] * inv};
            *(f32x4*)(op + ks * 32 + 4) = (f32x4){o[ks][4] * inv, o[ks][5] * inv,
                                                  o[ks][6] * inv, o[ks][7] * inv};
        }
    }
}

extern "C" void kernel_launch(void* const* d_in, const int* in_sizes, int n_in,
                              void* d_out, int out_size, void* d_ws, size_t ws_size,
                              hipStream_t stream) {
    const float* tgt  = (const float*)d_in[0];
    const float* hist = (const float*)d_in[1];
    const int*   mask = (const int*)d_in[2];
    const float* W1   = (const float*)d_in[3];
    const float* b1   = (const float*)d_in[4];
    const float* W2   = (const float*)d_in[5];
    const float* b2   = (const float*)d_in[6];
    (void)b2;  // cancels in softmax
    float* out = (float*)d_out;
    char* ws = (char*)d_ws;

    prep_fold<<<64, 128, 0, stream>>>(W1, ws);
    prep_ta<<<B_ / 4, 256, 0, stream>>>(tgt, b1, ws);
    mask_build<<<B_ / 4, 256, 0, stream>>>(mask, tgt, ws);
    din_fused<<<B_ / 4, 256, 0, stream>>>(hist, W2, ws, out);
}

// Round 15
// 56.391 us; speedup vs baseline: 1.4336x; 1.0235x over previous
//
#include <hip/hip_runtime.h>
#include <hip/hip_bf16.h>

typedef __attribute__((ext_vector_type(8))) short bf16x8;
typedef __attribute__((ext_vector_type(4))) float f32x4;

#define B_ 2048
#define S_ 200
#define D_ 128
#define H_ 64
#define LOG2E 1.44269504f
#define TR 16                     /* rows per tile */
#define TB 8192                   /* bytes per hist buffer */

// ws layout
#define WS_AC 0u                  // f32 acT[64][128] (W1a+W1c)      = 32 KB
#define WS_WB 32768u              // bf16 W' [n=64][k=256] swizzled  = 32 KB
#define WS_MT 65536u              // meta[2048][2048 B]              =  4 MB
// meta: [0,512) t fp32 | [512,768) tA fp32 | [768] cnt|uni<<16 | [1024,1856) list i32[208]

static __device__ __forceinline__ short f2bf_hw(float f) {
    return (short)__builtin_bit_cast(unsigned short, __float2bfloat16(f));  // RNE
}

static __device__ __forceinline__ void gload16(const void* g, void* l) {
    __builtin_amdgcn_global_load_lds(
        (const __attribute__((address_space(1))) unsigned int*)g,
        (__attribute__((address_space(3))) unsigned int*)l, 16, 0, 0);
}

// ---- prep A: acT fp32 + bf16 W' image in the exact swizzled LDS layout ----
__global__ __launch_bounds__(128)
void prep_fold(const float* __restrict__ W1, char* __restrict__ ws)
{
    const int n = blockIdx.x;       // 64
    const int k = threadIdx.x;      // 128
    float a = W1[k * H_ + n];
    float b = W1[(128 + k) * H_ + n];
    float c = W1[(256 + k) * H_ + n];
    float d = W1[(384 + k) * H_ + n];
    ((float*)(ws + WS_AC))[n * 128 + k] = a + c;
    char* img = ws + WS_WB;
    const int sw = (n & 7) << 4;
    const int kk = k >> 3, e2 = (k & 7) * 2;
    *(short*)(img + n * 512 + ((kk * 16) ^ sw) + e2)        = f2bf_hw(b - c);
    *(short*)(img + n * 512 + (((16 + kk) * 16) ^ sw) + e2) = f2bf_hw(d);
}

// ---- prep B: exact fp32 tA[b][n] -> meta+512 ----
__global__ __launch_bounds__(256)
void prep_ta(const float* __restrict__ tgt, const float* __restrict__ b1,
             char* __restrict__ ws)
{
    __shared__ float tl[4][128];
    const int tid = threadIdx.x;
    const int b0 = blockIdx.x * 4;
    if (tid < 128) {
        int bb = tid >> 5, q = tid & 31;
        *(float4*)&tl[bb][q * 4] = ((const float4*)(tgt + (size_t)(b0 + bb) * D_))[q];
    }
    __syncthreads();
    const int n = tid & 63, bb = tid >> 6;
    const float* ac = (const float*)(ws + WS_AC) + n * 128;
    float s = 0.f;
    #pragma unroll 8
    for (int d = 0; d < 128; ++d) s = fmaf(tl[bb][d], ac[d], s);
    ((float*)(ws + WS_MT + (size_t)(b0 + bb) * 2048u + 512u))[n] = s + b1[n];
}

// ---- prep C: compact active rows + copy t ; one wave per batch ----
__global__ __launch_bounds__(256)
void mask_build(const int* __restrict__ mask, const float* __restrict__ tgt,
                char* __restrict__ ws)
{
    const int lane = threadIdx.x & 63;
    const int wv   = threadIdx.x >> 6;
    const int b    = blockIdx.x * 4 + wv;
    const int* mp  = mask + (size_t)b * S_;
    char* mt = ws + WS_MT + (size_t)b * 2048u;
    int* lst = (int*)(mt + 1024);
    int cnt = 0, last = 0;
    #pragma unroll
    for (int c = 0; c < 4; ++c) {
        int s = c * 64 + lane;
        int m = (s < S_) ? mp[s] : 0;
        unsigned long long bal = __ballot(m != 0);
        if (m) lst[cnt + __builtin_popcountll(bal & ((1ull << lane) - 1ull))] = s;
        if (bal) last = c * 64 + (63 - __builtin_clzll(bal));
        cnt += __builtin_popcountll(bal);
    }
    int uni = 0;
    if (cnt == 0) { uni = 1; cnt = S_; }
    for (int p = cnt + lane; p < 208; p += 64) lst[p] = uni ? (S_ - 1) : last;
    if (uni)
        for (int p = lane; p < S_; p += 64) lst[p] = p;
    if (lane == 0) *(int*)(mt + 768) = cnt | (uni << 16);
    if (lane < 32) ((float4*)mt)[lane] = ((const float4*)(tgt + (size_t)b * D_))[lane];
}

// ---- fused: block = 4 batches, WAVE = 1 batch. TR=16 (full MFMA rows);
// W' h-frags + t hoisted to VGPR (prologue); per-tile LDS = 8 hist + 16 W'd.
// LDS 136 KB -> 1 block/CU, amdgpu_waves_per_eu(1,1) -> full VGPR budget. ----
__global__ __launch_bounds__(256) __attribute__((amdgpu_waves_per_eu(1, 1)))
void din_fused(const float* __restrict__ hist, const float* __restrict__ W2,
               const char* __restrict__ ws, float* __restrict__ out)
{
    __shared__ __align__(16) char L[139264];  // 32K W' + 4*(2K meta + 3*8K bufs)
    const int tid  = threadIdx.x;
    const int lane = tid & 63;
    const int wv   = tid >> 6;
    const int b    = blockIdx.x * 4 + wv;
    const int lo   = lane & 15;
    const int hi   = lane >> 4;
    char* Lm = L + 32768 + wv * 26624;

    // w2 (global reg loads; drained by the prologue barrier)
    f32x4 w2v[4];
    #pragma unroll
    for (int ng = 0; ng < 4; ++ng) {
        f32x4 wl = *(const f32x4*)(W2 + ng * 16 + hi * 4);
        w2v[ng] = (f32x4){wl[0] * LOG2E, wl[1] * LOG2E, wl[2] * LOG2E, wl[3] * LOG2E};
    }

    // prologue glls: W' quarter (8 KB/wave) + meta (2 KB/wave)
    {
        const char* wsrc = ws + WS_WB + wv * 8192 + (size_t)lane * 16u;
        #pragma unroll
        for (int i = 0; i < 8; ++i)
            gload16(wsrc + i * 1024, L + wv * 8192 + i * 1024);
        const char* msrc = ws + WS_MT + (size_t)b * 2048u + (size_t)lane * 16u;
        gload16(msrc,        Lm);
        gload16(msrc + 1024, Lm + 1024);
    }
    asm volatile("s_waitcnt vmcnt(0)" ::: "memory");
    __syncthreads();                          // W' (all waves) + meta visible

    const int cw  = *(const int*)(Lm + 768);
    const int cnt = cw & 0xffff;
    const int uni = cw >> 16;
    const int nt  = (cnt + 15) >> 4;          // >= 1 (cnt >= 1 always)
    const int* ll = (const int*)(Lm + 1024);

    f32x4 tav[4];
    #pragma unroll
    for (int ng = 0; ng < 4; ++ng)
        tav[ng] = *(const f32x4*)(Lm + 512 + (ng * 16 + hi * 4) * 4);
    // hoist t (this lane's 32 k-values)
    f32x4 tp0[4], tp1[4];
    #pragma unroll
    for (int ks = 0; ks < 4; ++ks) {
        tp0[ks] = *(const f32x4*)(Lm + ks * 128 + hi * 32);
        tp1[ks] = *(const f32x4*)(Lm + ks * 128 + hi * 32 + 16);
    }

    int abase[4], akoff[8];
    #pragma unroll
    for (int ng = 0; ng < 4; ++ng) abase[ng] = (ng * 16 + lo) * 512;
    #pragma unroll
    for (int ks = 0; ks < 8; ++ks) akoff[ks] = (ks * 64 + hi * 16) ^ ((lo & 7) << 4);
    // hoist W' h-part fragments (loop-invariant; 64 VGPR)
    bf16x8 bfH[4][4];
    #pragma unroll
    for (int ks = 0; ks < 4; ++ks)
        #pragma unroll
        for (int ng = 0; ng < 4; ++ng)
            bfH[ks][ng] = *(const bf16x8*)(L + abase[ng] + akoff[ks]);

    const int rb = (lo * 512 + hi * 32) ^ ((lo & 7) << 4);
    char* BB0 = Lm + 2048;
    char* BB1 = Lm + 2048 + TB;
    char* BB2 = Lm + 2048 + 2 * TB;

    const char* hb = (const char*)hist + (size_t)b * (S_ * D_ * 4);
    const int cp = (lane & 31) * 16;
    const int h5 = lane >> 5;
    auto stage = [&](int t, char* bufp) {
        #pragma unroll
        for (int i = 0; i < 8; ++i) {
            int r = 2 * i + h5;
            int rr = ll[t * 16 + r];
            gload16(hb + (size_t)rr * 512 + (cp ^ ((r & 7) << 4)), bufp + i * 1024);
        }
    };
    stage(0, BB0);
    stage(nt > 1 ? 1 : 0, BB1);
    stage(nt > 2 ? 2 : nt - 1, BB2);

    float o[4][8];
    #pragma unroll
    for (int ks = 0; ks < 4; ++ks)
        #pragma unroll
        for (int e = 0; e < 8; ++e) o[ks][e] = 0.f;
    float l = 0.f, mx = -1e30f;

    // uniform vmcnt(16): issues 0..t+2 exist when computing t (2 tiles in flight)
    #pragma unroll 1
    for (int t = 0; t < nt; ++t) {
        char* buf = (t % 3 == 0) ? BB0 : (t % 3 == 1) ? BB1 : BB2;
        asm volatile("s_waitcnt vmcnt(16)" ::: "memory");
        __builtin_amdgcn_sched_barrier(0);
        // hist fp32 (kept live: QK cvt AND PV use these regs)
        f32x4 h0[4], h1[4];
        #pragma unroll
        for (int ks = 0; ks < 4; ++ks) {
            int o4 = rb + ks * 128;
            h0[ks] = *(const f32x4*)(buf + o4);
            h1[ks] = *(const f32x4*)(buf + (o4 ^ 16));
        }
        asm volatile("s_waitcnt lgkmcnt(0)" ::: "memory");
        __builtin_amdgcn_sched_barrier(0);
        if (t + 1 < nt) {                     // keep issue count uniform; skip on last
            int ts = t + 3; if (ts > nt - 1) ts = nt - 1;
            stage(ts, buf);                   // just-consumed slot; clamped dup hits L2
        }
        // QK: K=256 = [h | t*h]
        f32x4 acc[4];
        #pragma unroll
        for (int ng = 0; ng < 4; ++ng) acc[ng] = (f32x4){0.f, 0.f, 0.f, 0.f};
        #pragma unroll
        for (int ks = 0; ks < 4; ++ks) {
            bf16x8 bh, bt;
            #pragma unroll
            for (int e = 0; e < 4; ++e) {
                bh[e]     = f2bf_hw(h0[ks][e]);
                bh[e + 4] = f2bf_hw(h1[ks][e]);
                bt[e]     = f2bf_hw(tp0[ks][e] * h0[ks][e]);   // fp32 product, RNE
                bt[e + 4] = f2bf_hw(tp1[ks][e] * h1[ks][e]);
            }
            #pragma unroll
            for (int ng = 0; ng < 4; ++ng)
                acc[ng] = __builtin_amdgcn_mfma_f32_16x16x32_bf16(bfH[ks][ng], bh, acc[ng], 0, 0, 0);
            #pragma unroll
            for (int ng = 0; ng < 4; ++ng) {
                bf16x8 afd = *(const bf16x8*)(L + abase[ng] + akoff[ks + 4]);
                acc[ng] = __builtin_amdgcn_mfma_f32_16x16x32_bf16(afd, bt, acc[ng], 0, 0, 0);
            }
        }
        // lane-local relu-dot over 16 n-values; s-row = t*16 + lo
        float s0 = 0.f, s1 = 0.f, s2 = 0.f, s3 = 0.f;
        #pragma unroll
        for (int e = 0; e < 4; ++e) {
            s0 = fmaf(fmaxf(acc[0][e] + tav[0][e], 0.f), w2v[0][e], s0);
            s1 = fmaf(fmaxf(acc[1][e] + tav[1][e], 0.f), w2v[1][e], s1);
            s2 = fmaf(fmaxf(acc[2][e] + tav[2][e], 0.f), w2v[2][e], s2);
            s3 = fmaf(fmaxf(acc[3][e] + tav[3][e], 0.f), w2v[3][e], s3);
        }
        float sum = (s0 + s1) + (s2 + s3);
        sum += __shfl_xor(sum, 16);
        sum += __shfl_xor(sum, 32);
        const bool valid = (t * 16 + lo) < cnt;
        float lg = uni ? (valid ? 0.f : -1e30f) : (valid ? sum : -1e30f);
        float tm = lg;
        tm = fmaxf(tm, __shfl_xor(tm, 1));
        tm = fmaxf(tm, __shfl_xor(tm, 2));
        tm = fmaxf(tm, __shfl_xor(tm, 4));
        tm = fmaxf(tm, __shfl_xor(tm, 8));
        if (tm > mx + 11.5f) {                // defer-rescale (T13)
            float rsc = exp2f(mx - tm);
            #pragma unroll
            for (int ks = 0; ks < 4; ++ks)
                #pragma unroll
                for (int e = 0; e < 8; ++e) o[ks][e] *= rsc;
            l *= rsc;
            mx = tm;
        }
        float p = valid ? exp2f(lg - mx) : 0.f;
        l += p;
        // PV from the live h registers (no LDS re-read)
        #pragma unroll
        for (int ks = 0; ks < 4; ++ks) {
            o[ks][0] = fmaf(p, h0[ks][0], o[ks][0]);
            o[ks][1] = fmaf(p, h0[ks][1], o[ks][1]);
            o[ks][2] = fmaf(p, h0[ks][2], o[ks][2]);
            o[ks][3] = fmaf(p, h0[ks][3], o[ks][3]);
            o[ks][4] = fmaf(p, h1[ks][0], o[ks][4]);
            o[ks][5] = fmaf(p, h1[ks][1], o[ks][5]);
            o[ks][6] = fmaf(p, h1[ks][2], o[ks][6]);
            o[ks][7] = fmaf(p, h1[ks][3], o[ks][7]);
        }
    }

    // ---- epilogue: lo-reduce, direct stores ----
    #pragma unroll
    for (int ks = 0; ks < 4; ++ks)
        #pragma unroll
        for (int e = 0; e < 8; ++e) {
            float v = o[ks][e];
            v += __shfl_xor(v, 1);
            v += __shfl_xor(v, 2);
            v += __shfl_xor(v, 4);
            v += __shfl_xor(v, 8);
            o[ks][e] = v;
        }
    l += __shfl_xor(l, 1);
    l += __shfl_xor(l, 2);
    l += __shfl_xor(l, 4);
    l += __shfl_xor(l, 8);

    const float inv = 1.0f / l;               // mx, b2 cancel in softmax
    if (lo == 0) {
        float* op = out + (size_t)b * D_ + hi * 8;
        #pragma unroll
        for (int ks = 0; ks < 4; ++ks) {
            *(f32x4*)(op + ks * 32)     = (f32x4){o[ks][0] * inv, o[ks][1] * inv,
                                                  o[ks][2] * inv, o[ks][3] * inv};
            *(f32x4*)(op + ks * 32 + 4) = (f32x4){o[ks][4] * inv, o[ks][5] * inv,
                                                  o[ks][6] * inv, o[ks][7] * inv};
        }
    }
}

extern "C" void kernel_launch(void* const* d_in, const int* in_sizes, int n_in,
                              void* d_out, int out_size, void* d_ws, size_t ws_size,
                              hipStream_t stream) {
    const float* tgt  = (const float*)d_in[0];
    const float* hist = (const float*)d_in[1];
    const int*   mask = (const int*)d_in[2];
    const float* W1   = (const float*)d_in[3];
    const float* b1   = (const float*)d_in[4];
    const float* W2   = (const float*)d_in[5];
    const float* b2   = (const float*)d_in[6];
    (void)b2;  // cancels in softmax
    float* out = (float*)d_out;
    char* ws = (char*)d_ws;

    prep_fold<<<64, 128, 0, stream>>>(W1, ws);
    prep_ta<<<B_ / 4, 256, 0, stream>>>(tgt, b1, ws);
    mask_build<<<B_ / 4, 256, 0, stream>>>(mask, tgt, ws);
    din_fused<<<B_ / 4, 256, 0, stream>>>(hist, W2, ws, out);
}

// Round 16
// 51.339 us; speedup vs baseline: 1.5747x; 1.0984x over previous
//
#include <hip/hip_runtime.h>
#include <hip/hip_bf16.h>

typedef __attribute__((ext_vector_type(8))) short bf16x8;
typedef __attribute__((ext_vector_type(4))) float f32x4;

#define B_ 2048
#define S_ 200
#define D_ 128
#define H_ 64
#define LOG2E 1.44269504f
#define TR 16                     /* rows per tile */
#define TB 8192                   /* bytes per hist buffer */

// ws layout
#define WS_AC 0u                  // f32 acKN[k=128][n=64] (W1a+W1c, k-major) = 32 KB
#define WS_WB 32768u              // bf16 W' [n=64][k=256] swizzled image     = 32 KB

static __device__ __forceinline__ short f2bf_hw(float f) {
    return (short)__builtin_bit_cast(unsigned short, __float2bfloat16(f));  // RNE
}

static __device__ __forceinline__ void gload16(const void* g, void* l) {
    __builtin_amdgcn_global_load_lds(
        (const __attribute__((address_space(1))) unsigned int*)g,
        (__attribute__((address_space(3))) unsigned int*)l, 16, 0, 0);
}

// ---- prep: acKN fp32 (k-major) + bf16 W' image in the exact swizzled layout ----
// W'[k][n] = k<128 ? (W1b-W1c)[k][n] : W1d[k-128][n]
__global__ __launch_bounds__(128)
void prep_fold(const float* __restrict__ W1, char* __restrict__ ws)
{
    const int n = blockIdx.x;       // 64
    const int k = threadIdx.x;      // 128
    float a = W1[k * H_ + n];
    float b = W1[(128 + k) * H_ + n];
    float c = W1[(256 + k) * H_ + n];
    float d = W1[(384 + k) * H_ + n];
    ((float*)(ws + WS_AC))[k * 64 + n] = a + c;       // k-major for coalesced tA loop
    char* img = ws + WS_WB;
    const int sw = (n & 7) << 4;
    const int kk = k >> 3, e2 = (k & 7) * 2;
    *(short*)(img + n * 512 + ((kk * 16) ^ sw) + e2)        = f2bf_hw(b - c);
    *(short*)(img + n * 512 + (((16 + kk) * 16) ^ sw) + e2) = f2bf_hw(d);
}

// ---- fused: block = 4 batches, WAVE = 1 batch; in-wave meta (mask compaction,
// exact fp32 tA); TR=16, 3-deep counted-vmcnt pipeline; hoisted W'h/t frags. ----
__global__ __launch_bounds__(256) __attribute__((amdgpu_waves_per_eu(1, 1)))
void din_fused(const float* __restrict__ tgt, const float* __restrict__ hist,
               const int* __restrict__ mask, const float* __restrict__ W2,
               const float* __restrict__ b1, const char* __restrict__ ws,
               float* __restrict__ out)
{
    __shared__ __align__(16) char L[139264];  // 32K W' + 4*(2K meta + 3*8K bufs)
    const int tid  = threadIdx.x;
    const int lane = tid & 63;
    const int wv   = tid >> 6;
    const int b    = blockIdx.x * 4 + wv;
    const int lo   = lane & 15;
    const int hi   = lane >> 4;
    char* Lm = L + 32768 + wv * 26624;        // meta: [512,768) tA | [1024,1856) list

    // --- issue W' quarter glls first (drained at the barrier) ---
    {
        const char* wsrc = ws + WS_WB + wv * 8192 + (size_t)lane * 16u;
        #pragma unroll
        for (int i = 0; i < 8; ++i)
            gload16(wsrc + i * 1024, L + wv * 8192 + i * 1024);
    }

    // --- w2, t fragments (register loads) ---
    f32x4 w2v[4];
    #pragma unroll
    for (int ng = 0; ng < 4; ++ng) {
        f32x4 wl = *(const f32x4*)(W2 + ng * 16 + hi * 4);
        w2v[ng] = (f32x4){wl[0] * LOG2E, wl[1] * LOG2E, wl[2] * LOG2E, wl[3] * LOG2E};
    }
    f32x4 tp0[4], tp1[4];
    #pragma unroll
    for (int ks = 0; ks < 4; ++ks) {
        tp0[ks] = *(const f32x4*)(tgt + (size_t)b * D_ + ks * 32 + hi * 8);
        tp1[ks] = *(const f32x4*)(tgt + (size_t)b * D_ + ks * 32 + hi * 8 + 4);
    }

    // --- in-wave mask compaction (own batch) ---
    int* lst = (int*)(Lm + 1024);
    int cnt = 0, uni = 0;
    {
        const int* mp = mask + (size_t)b * S_;
        int last = 0;
        #pragma unroll
        for (int c = 0; c < 4; ++c) {
            int s = c * 64 + lane;
            int m = (s < S_) ? mp[s] : 0;
            unsigned long long bal = __ballot(m != 0);
            if (m) lst[cnt + __builtin_popcountll(bal & ((1ull << lane) - 1ull))] = s;
            if (bal) last = c * 64 + (63 - __builtin_clzll(bal));
            cnt += __builtin_popcountll(bal);
        }
        if (cnt == 0) { uni = 1; cnt = S_; }
        for (int p = cnt + lane; p < 208; p += 64) lst[p] = uni ? (S_ - 1) : last;
        if (uni)
            for (int p = lane; p < S_; p += 64) lst[p] = p;
    }

    // --- in-wave exact fp32 tA: lane computes n = lane ---
    // t[d] is wave-uniform (s_loads); acKN k-major -> coalesced per-lane reads (L2-hot)
    {
        const float* ak = (const float*)(ws + WS_AC) + lane;
        const float* tb = tgt + (size_t)b * D_;
        float ta = 0.f;
        #pragma unroll 16
        for (int d = 0; d < 128; ++d)
            ta = fmaf(tb[d], ak[d * 64], ta);
        ta += b1[lane];
        *(float*)(Lm + 512 + lane * 4) = ta;
    }
    f32x4 tav[4];
    #pragma unroll
    for (int ng = 0; ng < 4; ++ng)
        tav[ng] = *(const f32x4*)(Lm + 512 + (ng * 16 + hi * 4) * 4);

    asm volatile("s_waitcnt vmcnt(0)" ::: "memory");
    __syncthreads();                          // W' (all waves' quarters) visible

    const int nt = (cnt + 15) >> 4;           // >= 1
    const int* ll = (const int*)(Lm + 1024);

    int abase[4], akoff[8];
    #pragma unroll
    for (int ng = 0; ng < 4; ++ng) abase[ng] = (ng * 16 + lo) * 512;
    #pragma unroll
    for (int ks = 0; ks < 8; ++ks) akoff[ks] = (ks * 64 + hi * 16) ^ ((lo & 7) << 4);
    // hoist W' h-part fragments (loop-invariant)
    bf16x8 bfH[4][4];
    #pragma unroll
    for (int ks = 0; ks < 4; ++ks)
        #pragma unroll
        for (int ng = 0; ng < 4; ++ng)
            bfH[ks][ng] = *(const bf16x8*)(L + abase[ng] + akoff[ks]);

    const int rb = (lo * 512 + hi * 32) ^ ((lo & 7) << 4);
    char* BB0 = Lm + 2048;
    char* BB1 = Lm + 2048 + TB;
    char* BB2 = Lm + 2048 + 2 * TB;

    const char* hb = (const char*)hist + (size_t)b * (S_ * D_ * 4);
    const int cp = (lane & 31) * 16;
    const int h5 = lane >> 5;
    auto stage = [&](int t, char* bufp) {
        #pragma unroll
        for (int i = 0; i < 8; ++i) {
            int r = 2 * i + h5;
            int rr = ll[t * 16 + r];
            gload16(hb + (size_t)rr * 512 + (cp ^ ((r & 7) << 4)), bufp + i * 1024);
        }
    };
    stage(0, BB0);
    stage(nt > 1 ? 1 : 0, BB1);
    stage(nt > 2 ? 2 : nt - 1, BB2);

    float o[4][8];
    #pragma unroll
    for (int ks = 0; ks < 4; ++ks)
        #pragma unroll
        for (int e = 0; e < 8; ++e) o[ks][e] = 0.f;
    float l = 0.f, mx = -1e30f;

    // uniform vmcnt(16): when computing t, tiles t+1,t+2 stay in flight
    #pragma unroll 1
    for (int t = 0; t < nt; ++t) {
        char* buf = (t % 3 == 0) ? BB0 : (t % 3 == 1) ? BB1 : BB2;
        asm volatile("s_waitcnt vmcnt(16)" ::: "memory");
        __builtin_amdgcn_sched_barrier(0);
        f32x4 h0[4], h1[4];
        #pragma unroll
        for (int ks = 0; ks < 4; ++ks) {
            int o4 = rb + ks * 128;
            h0[ks] = *(const f32x4*)(buf + o4);
            h1[ks] = *(const f32x4*)(buf + (o4 ^ 16));
        }
        asm volatile("s_waitcnt lgkmcnt(0)" ::: "memory");
        __builtin_amdgcn_sched_barrier(0);
        if (t + 1 < nt) {
            int ts = t + 3; if (ts > nt - 1) ts = nt - 1;
            stage(ts, buf);                   // just-consumed slot; clamped dup hits L2
        }
        // QK: K=256 = [h | t*h]
        f32x4 acc[4];
        #pragma unroll
        for (int ng = 0; ng < 4; ++ng) acc[ng] = (f32x4){0.f, 0.f, 0.f, 0.f};
        #pragma unroll
        for (int ks = 0; ks < 4; ++ks) {
            bf16x8 bh, bt;
            #pragma unroll
            for (int e = 0; e < 4; ++e) {
                bh[e]     = f2bf_hw(h0[ks][e]);
                bh[e + 4] = f2bf_hw(h1[ks][e]);
                bt[e]     = f2bf_hw(tp0[ks][e] * h0[ks][e]);   // fp32 product, RNE
                bt[e + 4] = f2bf_hw(tp1[ks][e] * h1[ks][e]);
            }
            #pragma unroll
            for (int ng = 0; ng < 4; ++ng)
                acc[ng] = __builtin_amdgcn_mfma_f32_16x16x32_bf16(bfH[ks][ng], bh, acc[ng], 0, 0, 0);
            #pragma unroll
            for (int ng = 0; ng < 4; ++ng) {
                bf16x8 afd = *(const bf16x8*)(L + abase[ng] + akoff[ks + 4]);
                acc[ng] = __builtin_amdgcn_mfma_f32_16x16x32_bf16(afd, bt, acc[ng], 0, 0, 0);
            }
        }
        // lane-local relu-dot over 16 n-values; s-row = t*16 + lo
        float s0 = 0.f, s1 = 0.f, s2 = 0.f, s3 = 0.f;
        #pragma unroll
        for (int e = 0; e < 4; ++e) {
            s0 = fmaf(fmaxf(acc[0][e] + tav[0][e], 0.f), w2v[0][e], s0);
            s1 = fmaf(fmaxf(acc[1][e] + tav[1][e], 0.f), w2v[1][e], s1);
            s2 = fmaf(fmaxf(acc[2][e] + tav[2][e], 0.f), w2v[2][e], s2);
            s3 = fmaf(fmaxf(acc[3][e] + tav[3][e], 0.f), w2v[3][e], s3);
        }
        float sum = (s0 + s1) + (s2 + s3);
        sum += __shfl_xor(sum, 16);
        sum += __shfl_xor(sum, 32);
        const bool valid = (t * 16 + lo) < cnt;
        float lg = uni ? (valid ? 0.f : -1e30f) : (valid ? sum : -1e30f);
        float tm = lg;
        tm = fmaxf(tm, __shfl_xor(tm, 1));
        tm = fmaxf(tm, __shfl_xor(tm, 2));
        tm = fmaxf(tm, __shfl_xor(tm, 4));
        tm = fmaxf(tm, __shfl_xor(tm, 8));
        if (tm > mx + 11.5f) {                // defer-rescale (T13)
            float rsc = exp2f(mx - tm);
            #pragma unroll
            for (int ks = 0; ks < 4; ++ks)
                #pragma unroll
                for (int e = 0; e < 8; ++e) o[ks][e] *= rsc;
            l *= rsc;
            mx = tm;
        }
        float p = valid ? exp2f(lg - mx) : 0.f;
        l += p;
        // PV from the live h registers
        #pragma unroll
        for (int ks = 0; ks < 4; ++ks) {
            o[ks][0] = fmaf(p, h0[ks][0], o[ks][0]);
            o[ks][1] = fmaf(p, h0[ks][1], o[ks][1]);
            o[ks][2] = fmaf(p, h0[ks][2], o[ks][2]);
            o[ks][3] = fmaf(p, h0[ks][3], o[ks][3]);
            o[ks][4] = fmaf(p, h1[ks][0], o[ks][4]);
            o[ks][5] = fmaf(p, h1[ks][1], o[ks][5]);
            o[ks][6] = fmaf(p, h1[ks][2], o[ks][6]);
            o[ks][7] = fmaf(p, h1[ks][3], o[ks][7]);
        }
    }

    // ---- epilogue: lo-reduce, direct stores ----
    #pragma unroll
    for (int ks = 0; ks < 4; ++ks)
        #pragma unroll
        for (int e = 0; e < 8; ++e) {
            float v = o[ks][e];
            v += __shfl_xor(v, 1);
            v += __shfl_xor(v, 2);
            v += __shfl_xor(v, 4);
            v += __shfl_xor(v, 8);
            o[ks][e] = v;
        }
    l += __shfl_xor(l, 1);
    l += __shfl_xor(l, 2);
    l += __shfl_xor(l, 4);
    l += __shfl_xor(l, 8);

    const float inv = 1.0f / l;               // mx, b2 cancel in softmax
    if (lo == 0) {
        float* op = out + (size_t)b * D_ + hi * 8;
        #pragma unroll
        for (int ks = 0; ks < 4; ++ks) {
            *(f32x4*)(op + ks * 32)     = (f32x4){o[ks][0] * inv, o[ks][1] * inv,
                                                  o[ks][2] * inv, o[ks][3] * inv};
            *(f32x4*)(op + ks * 32 + 4) = (f32x4){o[ks][4] * inv, o[ks][5] * inv,
                                                  o[ks][6] * inv, o[ks][7] * inv};
        }
    }
}

extern "C" void kernel_launch(void* const* d_in, const int* in_sizes, int n_in,
                              void* d_out, int out_size, void* d_ws, size_t ws_size,
                              hipStream_t stream) {
    const float* tgt  = (const float*)d_in[0];
    const float* hist = (const float*)d_in[1];
    const int*   mask = (const int*)d_in[2];
    const float* W1   = (const float*)d_in[3];
    const float* b1   = (const float*)d_in[4];
    const float* W2   = (const float*)d_in[5];
    const float* b2   = (const float*)d_in[6];
    (void)b2;  // cancels in softmax
    float* out = (float*)d_out;
    char* ws = (char*)d_ws;

    prep_fold<<<64, 128, 0, stream>>>(W1, ws);
    din_fused<<<B_ / 4, 256, 0, stream>>>(tgt, hist, mask, W2, b1, ws, out);
}